// Round 13
// baseline (525.942 us; speedup 1.0000x reference)
//
#include <hip/hip_runtime.h>
#include <hip/hip_bf16.h>
#include <math.h>

#define NN 20000
#define NE 320000
#define NG 128

using bf16x8 = __attribute__((ext_vector_type(8))) short;
using f32x4  = __attribute__((ext_vector_type(4))) float;

static __device__ __forceinline__ float lrelu(float v){ return v > 0.f ? v : 0.2f*v; }
static __device__ __forceinline__ float b2f(unsigned short u){ unsigned int v = ((unsigned int)u) << 16; return __uint_as_float(v); }
static __device__ __forceinline__ unsigned short f2b(float f){
  unsigned int x = __float_as_uint(f);
  unsigned int r = x + 0x7fffu + ((x >> 16) & 1u);
  return (unsigned short)(r >> 16);
}
static __device__ __forceinline__ void gl16(const unsigned short* g, unsigned short* l){
  __builtin_amdgcn_global_load_lds((const __attribute__((address_space(1))) void*)g,
                                   (__attribute__((address_space(3))) void*)l, 16, 0, 0);
}
static __device__ __forceinline__ uint4 bn8(uint4 u, const float* scs, const float* shs, int f0){
  float v[8] = { b2f(u.x & 0xffff), b2f(u.x >> 16), b2f(u.y & 0xffff), b2f(u.y >> 16),
                 b2f(u.z & 0xffff), b2f(u.z >> 16), b2f(u.w & 0xffff), b2f(u.w >> 16) };
  #pragma unroll
  for (int j = 0; j < 8; j++) v[j] = fmaxf(v[j]*scs[f0 + j] + shs[f0 + j], 0.f);
  uint4 p;
  p.x = (unsigned int)f2b(v[0]) | ((unsigned int)f2b(v[1]) << 16);
  p.y = (unsigned int)f2b(v[2]) | ((unsigned int)f2b(v[3]) << 16);
  p.z = (unsigned int)f2b(v[4]) | ((unsigned int)f2b(v[5]) << 16);
  p.w = (unsigned int)f2b(v[6]) | ((unsigned int)f2b(v[7]) << 16);
  return p;
}

// ---------------- CSR build ----------------
__global__ void k_hist3(const int* __restrict__ dst, const int* __restrict__ batch,
                        int* __restrict__ deg, int* __restrict__ gptr){
  int i = blockIdx.x*blockDim.x + threadIdx.x;
  if (i < NE){
    atomicAdd(&deg[dst[i]], 1);
  } else if (i <= NE + NN){
    int j = i - NE;
    if (j == 0){
      int b0 = batch[0];
      for (int g = 0; g <= b0; g++) gptr[g] = 0;
    } else if (j < NN){
      int b0 = batch[j-1], b1 = batch[j];
      for (int g = b0 + 1; g <= b1; g++) gptr[g] = j;
    } else {
      int b0 = batch[NN-1];
      for (int g = b0 + 1; g <= NG; g++) gptr[g] = NN;
    }
  }
}

__global__ void k_scan1(const int* __restrict__ deg, int* __restrict__ rowptr){
  __shared__ int tmp[1024];
  int t = threadIdx.x;
  const int CH = 20;
  int lo = t*CH, hi = min(lo + CH, NN);
  int loc[CH];
  int s = 0;
  for (int i = lo; i < hi; i++){ loc[i - lo] = deg[i]; s += loc[i - lo]; }
  tmp[t] = s; __syncthreads();
  for (int off = 1; off < 1024; off <<= 1){
    int u = (t >= off) ? tmp[t - off] : 0;
    __syncthreads();
    tmp[t] += u;
    __syncthreads();
  }
  int r = tmp[t] - s;
  if (t == 0) rowptr[0] = 0;
  for (int i = lo; i < hi; i++){ r += loc[i - lo]; rowptr[i + 1] = r; }
}

__global__ void k_fill(const int* __restrict__ src, const int* __restrict__ dst,
                       const int* __restrict__ ptr, int* __restrict__ cnt,
                       int* __restrict__ csrc){
  int e = blockIdx.x*blockDim.x + threadIdx.x;
  if (e < NE){
    int d = dst[e];
    int p = atomicAdd(&cnt[d], 1);
    csrc[ptr[d] + p] = src[e];
  }
}

// ---------------- weight prep (+x cast +wasd, one kernel) ----------------
struct WPrep {
  const float* W[9];
  unsigned short* Wt[9];
  int K[9];
  int Nn[9];
  int tileStart[10];
  const float* x;
  unsigned int* xb;
  int xEnd;                       // tileStart[9] + xblocks
  const float* asrc;
  const float* adst;
  unsigned short* Bt_sc;
};

__global__ __launch_bounds__(256)
void k_prep3(WPrep P){
  __shared__ float tile[64][65];
  __shared__ float av[128];
  int b = blockIdx.x;
  if (b < P.tileStart[9]){
    int i = 0;
    while (i < 8 && b >= P.tileStart[i+1]) i++;
    int ti = b - P.tileStart[i];
    int K = P.K[i], Nn = P.Nn[i];
    int ntc = Nn >> 6;
    int k0 = (ti / ntc) << 6, n0 = (ti % ntc) << 6;
    int c = threadIdx.x & 63, ro = threadIdx.x >> 6;
    const float* W = P.W[i];
    #pragma unroll
    for (int rr = 0; rr < 16; rr++){
      int r = rr*4 + ro;
      tile[c][r] = W[(size_t)(k0 + r)*Nn + n0 + c];
    }
    __syncthreads();
    unsigned short* Wt = P.Wt[i];
    if (i == 8){
      int hh = n0 >> 7, cl0 = n0 & 127;
      #pragma unroll
      for (int cc = 0; cc < 16; cc++){
        int cidx = cc*4 + ro;
        Wt[(size_t)(cl0 + cidx)*2048 + hh*256 + k0 + c] = f2b(tile[cidx][c]*0.125f);
      }
    } else {
      #pragma unroll
      for (int cc = 0; cc < 16; cc++){
        int cidx = cc*4 + ro;
        Wt[(size_t)(n0 + cidx)*K + k0 + c] = f2b(tile[cidx][c]);
      }
    }
  } else if (b < P.xEnd){
    int idx = (b - P.tileStart[9])*256 + threadIdx.x;
    if (idx < NN*64){
      unsigned int lo = f2b(P.x[2*idx]);
      unsigned int hi = f2b(P.x[2*idx + 1]);
      P.xb[idx] = lo | (hi << 16);
    }
  } else {
    int bb = b - P.xEnd;              // 0..15
    int h = bb & 7, isd = bb >> 3;
    int k = threadIdx.x;              // 0..255
    if (k < 128) av[k] = (isd ? P.adst : P.asrc)[h*128 + k];
    __syncthreads();
    const float* Wr = P.W[8] + (size_t)k*1024 + h*128;
    float s = 0.f;
    #pragma unroll 8
    for (int c = 0; c < 128; c++) s += Wr[c]*av[c];
    P.Bt_sc[bb*256 + k] = f2b(s);
  }
}

// ---------------- unified GIN aggregation (unroll-8) ----------------
template<int MODE, int DU>
__global__ __launch_bounds__(256)
void k_agg(const unsigned int* __restrict__ hU, const int* __restrict__ ptr,
           const int* __restrict__ csrc, unsigned int* __restrict__ z,
           const double* __restrict__ stats, const float* __restrict__ g,
           const float* __restrict__ bb, const float* __restrict__ bias){
  const int d = DU*2;
  __shared__ float scs[MODE == 1 ? 512 : 1];
  __shared__ float shs[MODE == 1 ? 512 : 1];
  int t = threadIdx.x;
  if (MODE == 1){
    for (int f = t; f < d; f += 256){
      double inv = 1.0 / (double)NN;
      double mu  = stats[f]*inv;
      double var = stats[d + f]*inv - mu*mu;
      if (var < 0.0) var = 0.0;
      float sc = g[f] * rsqrtf((float)var + 1e-5f);
      scs[f] = sc;
      shs[f] = bb[f] - (float)mu*sc;
    }
    __syncthreads();
  }
  const int npb = 256/DU;
  int n  = blockIdx.x*npb + t/DU;
  int tl = t & (DU - 1);
  int f0 = 2*tl, f1 = f0 + 1;
  float sc0 = 0.f, sh0 = 0.f, sc1 = 0.f, sh1 = 0.f;
  if (MODE == 1){ sc0 = scs[f0]; sh0 = shs[f0]; sc1 = scs[f1]; sh1 = shs[f1]; }
  int beg = ptr[n], deg = ptr[n+1] - beg;
  unsigned int self = hU[(size_t)n*DU + tl];
  float a0, a1;
  if (MODE == 1){
    a0 = fmaxf(b2f(self & 0xffff)*sc0 + sh0, 0.f);
    a1 = fmaxf(b2f(self >> 16)   *sc1 + sh1, 0.f);
  } else {
    a0 = b2f(self & 0xffff);
    a1 = b2f(self >> 16);
  }
  int i = 0;
  for (; i + 8 <= deg; i += 8){
    unsigned int v[8];
    #pragma unroll
    for (int u = 0; u < 8; u++) v[u] = hU[(size_t)csrc[beg + i + u]*DU + tl];
    #pragma unroll
    for (int u = 0; u < 8; u++){
      if (MODE == 1){
        a0 += fmaxf(b2f(v[u] & 0xffff)*sc0 + sh0, 0.f);
        a1 += fmaxf(b2f(v[u] >> 16)   *sc1 + sh1, 0.f);
      } else {
        a0 += b2f(v[u] & 0xffff);
        a1 += b2f(v[u] >> 16);
      }
    }
  }
  for (; i < deg; i++){
    unsigned int v = hU[(size_t)csrc[beg + i]*DU + tl];
    if (MODE == 1){
      a0 += fmaxf(b2f(v & 0xffff)*sc0 + sh0, 0.f);
      a1 += fmaxf(b2f(v >> 16)   *sc1 + sh1, 0.f);
    } else {
      a0 += b2f(v & 0xffff);
      a1 += b2f(v >> 16);
    }
  }
  if (MODE == 2){
    a0 = fmaxf(a0 + bias[f0], 0.f);
    a1 = fmaxf(a1 + bias[f1], 0.f);
  }
  z[(size_t)n*DU + tl] = (unsigned int)f2b(a0) | ((unsigned int)f2b(a1) << 16);
}

// ---------------- bf16 MFMA GEMM ----------------
template<int ACT, int OBF, int STATS, int PK, int BNA, int WBA>
__global__ __launch_bounds__(256)
void k_gemm_mfma(const unsigned short* __restrict__ A, const unsigned short* __restrict__ Bt,
                 const float* __restrict__ bias, float* __restrict__ C,
                 unsigned short* __restrict__ Cb, double* __restrict__ stats,
                 const double* __restrict__ bnst, const float* __restrict__ bng,
                 const float* __restrict__ bnb, unsigned short* __restrict__ Awb,
                 int M, int Nn, int K){
  const int LDA = BNA ? 40 : 32;
  __shared__ unsigned short As[2][128*(BNA ? 40 : 32)];
  __shared__ unsigned short Bs[2][128*32];
  __shared__ float scs[BNA ? 512 : 1];
  __shared__ float shs[BNA ? 512 : 1];
  const int bm = blockIdx.y*128, bn = blockIdx.x*128;
  const int tid = threadIdx.x;
  const int lane = tid & 63;
  const int wave = tid >> 6;
  const int wm = (wave >> 1)*64, wn = (wave & 1)*64;
  const int lr = lane & 15, lq = lane >> 4;

  f32x4 acc[4][4];
  #pragma unroll
  for (int i = 0; i < 4; i++)
    #pragma unroll
    for (int j = 0; j < 4; j++) acc[i][j] = (f32x4){0.f,0.f,0.f,0.f};

  const int rowA = tid >> 2, q = tid & 3;
  const int ldsOff = wave*16*32;
  const int gmA0 = min(bm + rowA,      M-1);
  const int gmA1 = min(bm + rowA + 64, M-1);
  const unsigned short* pA0 = &A[(size_t)gmA0*K + q*8];
  const unsigned short* pA1 = &A[(size_t)gmA1*K + q*8];
  const unsigned short* pB0 = &Bt[(size_t)(bn + rowA)*K + q*8];
  const unsigned short* pB1 = &Bt[(size_t)(bn + rowA + 64)*K + q*8];

  if (BNA){
    for (int f = tid; f < K; f += 256){
      double inv = 1.0 / (double)NN;
      double mu  = bnst[f]*inv;
      double var = bnst[K + f]*inv - mu*mu;
      if (var < 0.0) var = 0.0;
      float sc = bng[f] * rsqrtf((float)var + 1e-5f);
      scs[f] = sc;
      shs[f] = bnb[f] - (float)mu*sc;
    }
    __syncthreads();
  }

  if (BNA){
    uint4 u0 = *(const uint4*)pA0;
    uint4 u1 = *(const uint4*)pA1;
    int f0 = q*8;
    uint4 w0 = bn8(u0, scs, shs, f0);
    uint4 w1 = bn8(u1, scs, shs, f0);
    *(uint4*)&As[0][ rowA      *LDA + q*8] = w0;
    *(uint4*)&As[0][(rowA + 64)*LDA + q*8] = w1;
    if (WBA){
      *(uint4*)&Awb[(size_t)gmA0*K + q*8] = w0;
      *(uint4*)&Awb[(size_t)gmA1*K + q*8] = w1;
    }
  } else {
    gl16(pA0, &As[0][ldsOff]);
    gl16(pA1, &As[0][ldsOff] + 64*32);
  }
  gl16(pB0, &Bs[0][ldsOff]);
  gl16(pB1, &Bs[0][ldsOff] + 64*32);
  __syncthreads();

  int cur = 0;
  for (int k0 = 0; k0 < K; k0 += 32){
    const int kn = k0 + 32;
    uint4 nu0, nu1;
    if (kn < K){
      if (BNA){
        nu0 = *(const uint4*)(pA0 + kn);
        nu1 = *(const uint4*)(pA1 + kn);
      } else {
        gl16(pA0 + kn, &As[cur^1][ldsOff]);
        gl16(pA1 + kn, &As[cur^1][ldsOff] + 64*32);
      }
      gl16(pB0 + kn, &Bs[cur^1][ldsOff]);
      gl16(pB1 + kn, &Bs[cur^1][ldsOff] + 64*32);
    }
    bf16x8 af[4], bf[4];
    #pragma unroll
    for (int mi = 0; mi < 4; mi++)
      af[mi] = *(const bf16x8*)&As[cur][(wm + mi*16 + lr)*LDA + lq*8];
    #pragma unroll
    for (int ni = 0; ni < 4; ni++)
      bf[ni] = *(const bf16x8*)&Bs[cur][(wn + ni*16 + lr)*32 + lq*8];
    #pragma unroll
    for (int mi = 0; mi < 4; mi++)
      #pragma unroll
      for (int ni = 0; ni < 4; ni++)
        acc[mi][ni] = __builtin_amdgcn_mfma_f32_16x16x32_bf16(af[mi], bf[ni], acc[mi][ni], 0, 0, 0);
    if (BNA && kn < K){
      int f0 = kn + q*8;
      uint4 w0 = bn8(nu0, scs, shs, f0);
      uint4 w1 = bn8(nu1, scs, shs, f0);
      *(uint4*)&As[cur^1][ rowA      *LDA + q*8] = w0;
      *(uint4*)&As[cur^1][(rowA + 64)*LDA + q*8] = w1;
      if (WBA){
        *(uint4*)&Awb[(size_t)gmA0*K + kn + q*8] = w0;
        *(uint4*)&Awb[(size_t)gmA1*K + kn + q*8] = w1;
      }
    }
    __syncthreads();
    cur ^= 1;
  }

  float cs[4] = {0.f,0.f,0.f,0.f}, cq[4] = {0.f,0.f,0.f,0.f};
  #pragma unroll
  for (int mi = 0; mi < 4; mi++){
    #pragma unroll
    for (int j = 0; j < 4; j++){
      int gm = bm + wm + mi*16 + lq*4 + j;
      if (gm < M){
        #pragma unroll
        for (int ni = 0; ni < 4; ni++){
          int gn = bn + wn + ni*16 + lr;
          float v = acc[mi][ni][j] + (bias ? bias[gn] : 0.f);
          if (ACT) v = fmaxf(v, 0.f);
          if (PK){ if (gn < 16) C[(size_t)gm*16 + gn] = v; }
          else if (OBF) Cb[(size_t)gm*Nn + gn] = f2b(v);
          else     C [(size_t)gm*Nn + gn] = v;
          if (STATS){ cs[ni] += v; cq[ni] += v*v; }
        }
      }
    }
  }
  if (STATS){
    #pragma unroll
    for (int ni = 0; ni < 4; ni++){
      float s = cs[ni], qq = cq[ni];
      s += __shfl_xor(s, 16); s += __shfl_xor(s, 32);
      qq += __shfl_xor(qq, 16); qq += __shfl_xor(qq, 32);
      if (lane < 16){
        int gn = bn + wn + ni*16 + lr;
        atomicAdd(&stats[gn],      (double)s);
        atomicAdd(&stats[Nn + gn], (double)qq);
      }
    }
  }
}

// ---------------- fused GIN1 MLP ----------------
__global__ __launch_bounds__(256)
void k_gin1_mlp(const unsigned short* __restrict__ Z, const unsigned short* __restrict__ W1t,
                const float* __restrict__ b1, const unsigned short* __restrict__ W2t,
                const float* __restrict__ b2, unsigned short* __restrict__ Out,
                double* __restrict__ stats, int M){
  __shared__ unsigned short As[2][128*32];
  __shared__ unsigned short Bs[2][128*32];
  __shared__ unsigned short hid[128*136];
  const int bm = blockIdx.x*128;
  const int tid = threadIdx.x;
  const int lane = tid & 63;
  const int wave = tid >> 6;
  const int wm = (wave >> 1)*64, wn = (wave & 1)*64;
  const int lr = lane & 15, lq = lane >> 4;
  const int rowA = tid >> 2, q = tid & 3;
  const int ldsOff = wave*16*32;
  const int gm0 = min(bm + rowA,      M-1);
  const int gm1 = min(bm + rowA + 64, M-1);
  const unsigned short* pA0 = &Z[(size_t)gm0*128 + q*8];
  const unsigned short* pA1 = &Z[(size_t)gm1*128 + q*8];
  const unsigned short* pB0 = &W1t[(size_t)rowA*128 + q*8];
  const unsigned short* pB1 = &W1t[(size_t)(rowA + 64)*128 + q*8];

  f32x4 acc[4][4];
  #pragma unroll
  for (int i = 0; i < 4; i++)
    #pragma unroll
    for (int j = 0; j < 4; j++) acc[i][j] = (f32x4){0.f,0.f,0.f,0.f};

  gl16(pA0, &As[0][ldsOff]);
  gl16(pA1, &As[0][ldsOff] + 64*32);
  gl16(pB0, &Bs[0][ldsOff]);
  gl16(pB1, &Bs[0][ldsOff] + 64*32);
  __syncthreads();
  int cur = 0;
  for (int k0 = 0; k0 < 128; k0 += 32){
    int kn = k0 + 32;
    if (kn < 128){
      gl16(pA0 + kn, &As[cur^1][ldsOff]);
      gl16(pA1 + kn, &As[cur^1][ldsOff] + 64*32);
      gl16(pB0 + kn, &Bs[cur^1][ldsOff]);
      gl16(pB1 + kn, &Bs[cur^1][ldsOff] + 64*32);
    }
    bf16x8 af[4], bf[4];
    #pragma unroll
    for (int mi = 0; mi < 4; mi++)
      af[mi] = *(const bf16x8*)&As[cur][(wm + mi*16 + lr)*32 + lq*8];
    #pragma unroll
    for (int ni = 0; ni < 4; ni++)
      bf[ni] = *(const bf16x8*)&Bs[cur][(wn + ni*16 + lr)*32 + lq*8];
    #pragma unroll
    for (int mi = 0; mi < 4; mi++)
      #pragma unroll
      for (int ni = 0; ni < 4; ni++)
        acc[mi][ni] = __builtin_amdgcn_mfma_f32_16x16x32_bf16(af[mi], bf[ni], acc[mi][ni], 0, 0, 0);
    __syncthreads();
    cur ^= 1;
  }
  {
    float bv[4];
    #pragma unroll
    for (int ni = 0; ni < 4; ni++) bv[ni] = b1[wn + ni*16 + lr];
    #pragma unroll
    for (int mi = 0; mi < 4; mi++)
      #pragma unroll
      for (int j = 0; j < 4; j++){
        int row = wm + mi*16 + lq*4 + j;
        #pragma unroll
        for (int ni = 0; ni < 4; ni++){
          int col = wn + ni*16 + lr;
          hid[row*136 + col] = f2b(fmaxf(acc[mi][ni][j] + bv[ni], 0.f));
        }
      }
  }
  __syncthreads();

  f32x4 acc2[4][4];
  #pragma unroll
  for (int i = 0; i < 4; i++)
    #pragma unroll
    for (int j = 0; j < 4; j++) acc2[i][j] = (f32x4){0.f,0.f,0.f,0.f};
  const unsigned short* pC0 = &W2t[(size_t)rowA*128 + q*8];
  const unsigned short* pC1 = &W2t[(size_t)(rowA + 64)*128 + q*8];
  gl16(pC0, &Bs[0][ldsOff]);
  gl16(pC1, &Bs[0][ldsOff] + 64*32);
  __syncthreads();
  cur = 0;
  for (int k0 = 0; k0 < 128; k0 += 32){
    int kn = k0 + 32;
    if (kn < 128){
      gl16(pC0 + kn, &Bs[cur^1][ldsOff]);
      gl16(pC1 + kn, &Bs[cur^1][ldsOff] + 64*32);
    }
    bf16x8 af[4], bf[4];
    #pragma unroll
    for (int mi = 0; mi < 4; mi++)
      af[mi] = *(const bf16x8*)&hid[(wm + mi*16 + lr)*136 + k0 + lq*8];
    #pragma unroll
    for (int ni = 0; ni < 4; ni++)
      bf[ni] = *(const bf16x8*)&Bs[cur][(wn + ni*16 + lr)*32 + lq*8];
    #pragma unroll
    for (int mi = 0; mi < 4; mi++)
      #pragma unroll
      for (int ni = 0; ni < 4; ni++)
        acc2[mi][ni] = __builtin_amdgcn_mfma_f32_16x16x32_bf16(af[mi], bf[ni], acc2[mi][ni], 0, 0, 0);
    __syncthreads();
    cur ^= 1;
  }
  float cs[4] = {0.f,0.f,0.f,0.f}, cq[4] = {0.f,0.f,0.f,0.f};
  #pragma unroll
  for (int mi = 0; mi < 4; mi++){
    #pragma unroll
    for (int j = 0; j < 4; j++){
      int gm = bm + wm + mi*16 + lq*4 + j;
      if (gm < M){
        #pragma unroll
        for (int ni = 0; ni < 4; ni++){
          int gn = wn + ni*16 + lr;
          float v = acc2[mi][ni][j] + b2[gn];
          Out[(size_t)gm*128 + gn] = f2b(v);
          cs[ni] += v; cq[ni] += v*v;
        }
      }
    }
  }
  #pragma unroll
  for (int ni = 0; ni < 4; ni++){
    float s = cs[ni], qq = cq[ni];
    s += __shfl_xor(s, 16); s += __shfl_xor(s, 32);
    qq += __shfl_xor(qq, 16); qq += __shfl_xor(qq, 32);
    if (lane < 16){
      int gn = wn + ni*16 + lr;
      atomicAdd(&stats[gn],       (double)s);
      atomicAdd(&stats[128 + gn], (double)qq);
    }
  }
}

// ---------------- GAT: wave-per-node, 2-deep pipelined gather, pre-BN'd values ----------------
__global__ __launch_bounds__(256)
void k_gat_agg_w5(const unsigned int* __restrict__ hU4, const float* __restrict__ a_sd,
                  const int* __restrict__ ptr, const int* __restrict__ csrc,
                  unsigned int* __restrict__ agg){
  int wv = threadIdx.x >> 6, lane = threadIdx.x & 63;
  int n = blockIdx.x*4 + wv;
  int eslot = lane >> 3, hh = lane & 7;
  float adn = a_sd[n*16 + 8 + hh];
  int beg = ptr[n], deg = ptr[n+1] - beg, tot = deg + 1;

  float scb[8];
  int   sb[8];
  float m = -1e30f;
  #pragma unroll
  for (int c = 0; c < 8; c++){
    int e = c*8 + eslot;
    int s_ = (e < deg) ? csrc[beg + e] : n;
    sb[c] = s_;
    float v = (e < tot) ? lrelu(a_sd[s_*16 + hh] + adn) : -1e30f;
    scb[c] = v;
    m = fmaxf(m, v);
  }
  for (int e = 64 + eslot; e < tot; e += 8){
    int s_ = (e < deg) ? csrc[beg + e] : n;
    m = fmaxf(m, lrelu(a_sd[s_*16 + hh] + adn));
  }
  m = fmaxf(m, __shfl_xor(m, 8));
  m = fmaxf(m, __shfl_xor(m, 16));
  m = fmaxf(m, __shfl_xor(m, 32));
  float S = 0.f;
  #pragma unroll
  for (int c = 0; c < 8; c++){
    float e_ = __expf(scb[c] - m);      // -1e30 pad -> 0 exactly
    scb[c] = e_;
    S += e_;
  }
  for (int e = 64 + eslot; e < tot; e += 8){
    int s_ = (e < deg) ? csrc[beg + e] : n;
    S += __expf(lrelu(a_sd[s_*16 + hh] + adn) - m);
  }
  S += __shfl_xor(S, 8); S += __shfl_xor(S, 16); S += __shfl_xor(S, 32);
  float rinv = 1.f / (S + 1e-16f);
  #pragma unroll
  for (int c = 0; c < 8; c++) scb[c] *= rinv;

  float acc[8][4];
  #pragma unroll
  for (int h = 0; h < 8; h++)
    #pragma unroll
    for (int j = 0; j < 4; j++) acc[h][j] = 0.f;

  #pragma unroll
  for (int c = 0; c < 8; c++){
    if (c*8 >= tot) break;                       // wave-uniform; padded edges inside chunk have alpha=0
    int   sbc  = sb[c];
    float scbc = scb[c];
    int src0 = __shfl(sbc, 0);
    uint2 u = *(const uint2*)&hU4[(size_t)src0*128 + lane*2];
    #pragma unroll
    for (int ee = 0; ee < 8; ee++){
      uint2 un;
      if (ee < 7){
        int srcn = __shfl(sbc, (ee + 1)*8);
        un = *(const uint2*)&hU4[(size_t)srcn*128 + lane*2];
      }
      float al[8];
      #pragma unroll
      for (int h = 0; h < 8; h++) al[h] = __shfl(scbc, ee*8 + h);
      float v0 = b2f(u.x & 0xffff);
      float v1 = b2f(u.x >> 16);
      float v2 = b2f(u.y & 0xffff);
      float v3 = b2f(u.y >> 16);
      #pragma unroll
      for (int h = 0; h < 8; h++){
        acc[h][0] += al[h]*v0; acc[h][1] += al[h]*v1;
        acc[h][2] += al[h]*v2; acc[h][3] += al[h]*v3;
      }
      if (ee < 7) u = un;
    }
  }
  // overflow edges (tot > 64): recompute alpha per edge
  for (int e = 64; e < tot; e++){
    int s_ = (e < deg) ? csrc[beg + e] : n;
    float a = __expf(lrelu(a_sd[s_*16 + hh] + adn) - m)*rinv;
    float al[8];
    #pragma unroll
    for (int h = 0; h < 8; h++) al[h] = __shfl(a, h);
    uint2 u = *(const uint2*)&hU4[(size_t)s_*128 + lane*2];
    float v0 = b2f(u.x & 0xffff), v1 = b2f(u.x >> 16);
    float v2 = b2f(u.y & 0xffff), v3 = b2f(u.y >> 16);
    #pragma unroll
    for (int h = 0; h < 8; h++){
      acc[h][0] += al[h]*v0; acc[h][1] += al[h]*v1;
      acc[h][2] += al[h]*v2; acc[h][3] += al[h]*v3;
    }
  }

  #pragma unroll
  for (int h = 0; h < 8; h++){
    uint2 o;
    o.x = (unsigned int)f2b(acc[h][0]) | ((unsigned int)f2b(acc[h][1]) << 16);
    o.y = (unsigned int)f2b(acc[h][2]) | ((unsigned int)f2b(acc[h][3]) << 16);
    *(uint2*)&agg[(size_t)n*1024 + h*128 + lane*2] = o;
  }
}

// ---------------- BN5 + gate ----------------
__global__ __launch_bounds__(256)
void k_bn_relu_gate(const unsigned short* __restrict__ hpre, unsigned short* __restrict__ hb,
                    int total8, const double* __restrict__ stats,
                    const float* __restrict__ g, const float* __restrict__ b,
                    const float* __restrict__ gatew, const float* __restrict__ gateb,
                    float* __restrict__ logit){
  const int d = 128;
  __shared__ float scs[128], shs[128];
  for (int f = threadIdx.x; f < d; f += blockDim.x){
    double inv = 1.0 / (double)NN;
    double mu  = stats[f]*inv;
    double var = stats[d + f]*inv - mu*mu;
    if (var < 0.0) var = 0.0;
    float sc = g[f] * rsqrtf((float)var + 1e-5f);
    scs[f] = sc;
    shs[f] = b[f] - (float)mu*sc;
  }
  __syncthreads();
  int i = blockIdx.x*blockDim.x + threadIdx.x;
  if (i >= total8) return;
  int i8 = i*8;
  uint4 u = *(const uint4*)&hpre[i8];
  float v[8] = { b2f(u.x & 0xffff), b2f(u.x >> 16), b2f(u.y & 0xffff), b2f(u.y >> 16),
                 b2f(u.z & 0xffff), b2f(u.z >> 16), b2f(u.w & 0xffff), b2f(u.w >> 16) };
  int f0 = i8 & 127;
  float gp = 0.f;
  #pragma unroll
  for (int j = 0; j < 8; j++){
    float y = fmaxf(v[j]*scs[f0 + j] + shs[f0 + j], 0.f);
    v[j] = y;
    gp += y*gatew[f0 + j];
  }
  uint4 p;
  p.x = (unsigned int)f2b(v[0]) | ((unsigned int)f2b(v[1]) << 16);
  p.y = (unsigned int)f2b(v[2]) | ((unsigned int)f2b(v[3]) << 16);
  p.z = (unsigned int)f2b(v[4]) | ((unsigned int)f2b(v[5]) << 16);
  p.w = (unsigned int)f2b(v[6]) | ((unsigned int)f2b(v[7]) << 16);
  *(uint4*)&hb[i8] = p;
  #pragma unroll
  for (int o = 1; o < 16; o <<= 1) gp += __shfl_xor(gp, o);
  if ((threadIdx.x & 15) == 0) logit[i >> 4] = gp + gateb[0];
}

// ---------------- pooling + head fused ----------------
__global__ void k_poolhead(const unsigned short* __restrict__ h, const float* __restrict__ logit,
                           const int* __restrict__ gptr,
                           const float* __restrict__ w1, const float* __restrict__ b1,
                           const float* __restrict__ w2, const float* __restrict__ b2,
                           float* __restrict__ out){
  int g = blockIdx.x, t = threadIdx.x;   // 128
  int beg = gptr[g], end = gptr[g+1];
  __shared__ float red[128];
  __shared__ float prow[128];
  __shared__ float r1[128];
  __shared__ float m_sh, s_sh;
  float mx = -1e30f;
  for (int i = beg + t; i < end; i += 128) mx = fmaxf(mx, logit[i]);
  red[t] = mx; __syncthreads();
  for (int off = 64; off > 0; off >>= 1){ if (t < off) red[t] = fmaxf(red[t], red[t + off]); __syncthreads(); }
  if (t == 0) m_sh = red[0];
  __syncthreads();
  float sm = 0.f;
  for (int i = beg + t; i < end; i += 128) sm += __expf(logit[i] - m_sh);
  red[t] = sm; __syncthreads();
  for (int off = 64; off > 0; off >>= 1){ if (t < off) red[t] += red[t + off]; __syncthreads(); }
  if (t == 0) s_sh = red[0] + 1e-16f;
  __syncthreads();
  float acc = 0.f;
  for (int i = beg; i < end; i++){
    float w = __expf(logit[i] - m_sh) / s_sh;
    acc += w * b2f(h[(size_t)i*128 + t]);
  }
  prow[t] = acc;
  __syncthreads();
  float a = b1[t];
  for (int k = 0; k < 128; k++) a += prow[k]*w1[k*128 + t];
  a = fmaxf(a, 0.f);
  red[t] = a*w2[t*2 + 0]; r1[t] = a*w2[t*2 + 1];
  __syncthreads();
  for (int off = 64; off > 0; off >>= 1){
    if (t < off){ red[t] += red[t + off]; r1[t] += r1[t + off]; }
    __syncthreads();
  }
  if (t == 0){ out[g*2 + 0] = red[0] + b2[0]; out[g*2 + 1] = r1[0] + b2[1]; }
}

extern "C" void kernel_launch(void* const* d_in, const int* in_sizes, int n_in,
                              void* d_out, int out_size, void* d_ws, size_t ws_size,
                              hipStream_t stream) {
  const float* x        = (const float*)d_in[0];
  const int*   ei       = (const int*)  d_in[1];
  const int*   batch    = (const int*)  d_in[2];
  const float* gw1[4] = {(const float*)d_in[3],  (const float*)d_in[7],  (const float*)d_in[11], (const float*)d_in[15]};
  const float* gb1[4] = {(const float*)d_in[4],  (const float*)d_in[8],  (const float*)d_in[12], (const float*)d_in[16]};
  const float* gw2[4] = {(const float*)d_in[5],  (const float*)d_in[9],  (const float*)d_in[13], (const float*)d_in[17]};
  const float* gb2[4] = {(const float*)d_in[6],  (const float*)d_in[10], (const float*)d_in[14], (const float*)d_in[18]};
  const float* bng[5] = {(const float*)d_in[19], (const float*)d_in[21], (const float*)d_in[23], (const float*)d_in[25], (const float*)d_in[27]};
  const float* bnb[5] = {(const float*)d_in[20], (const float*)d_in[22], (const float*)d_in[24], (const float*)d_in[26], (const float*)d_in[28]};
  const float* gat_w    = (const float*)d_in[29];
  const float* gat_asrc = (const float*)d_in[30];
  const float* gat_adst = (const float*)d_in[31];
  const float* gat_bias = (const float*)d_in[32];
  const float* gate_w   = (const float*)d_in[33];
  const float* gate_b   = (const float*)d_in[34];
  const float* fc1_w    = (const float*)d_in[35];
  const float* fc1_b    = (const float*)d_in[36];
  const float* fc2_w    = (const float*)d_in[37];
  const float* fc2_b    = (const float*)d_in[38];
  const int* src = ei;
  const int* dst = ei + NE;

  char* wsb = (char*)d_ws;
  size_t off = 0;
  auto take = [&](size_t bytes) -> void* {
    void* p = wsb + off;
    off = (off + bytes + 255) & ~(size_t)255;
    return p;
  };
  unsigned short* hpre  = (unsigned short*)take((size_t)NN*512*2);
  unsigned short* hb    = (unsigned short*)take((size_t)NN*128*2);
  unsigned short* hb4   = (unsigned short*)take((size_t)NN*256*2);
  unsigned short* R     = (unsigned short*)take((size_t)NN*2048*2);
  unsigned short* z16   = R;
  unsigned short* hid16 = R + (size_t)NN*512;
  unsigned short* agg16 = R;
  unsigned short* xb    = (unsigned short*)take((size_t)NN*128*2);
  unsigned short* wt    = (unsigned short*)take((size_t)1000000*2);
  int*    deg    = (int*)   take((size_t)NN*4);
  int*    cnt    = (int*)   take((size_t)NN*4);
  double* statsA = (double*)take(2560*8);
  unsigned short* Bt_sc = (unsigned short*)take((size_t)128*256*2);
  float*  a_sd   = (float*) take((size_t)NN*16*4);
  float*  logit  = (float*) take((size_t)NN*4);
  int*    rowptr = (int*)   take((size_t)(NN+1)*4);
  int*    gptr   = (int*)   take((size_t)(NG+1)*4);
  int*    csrc   = (int*)   take((size_t)NE*4);
  (void)ws_size; (void)n_in; (void)in_sizes; (void)out_size;

  unsigned short* wt_g1w1 = wt;
  unsigned short* wt_g1w2 = wt_g1w1 + 128*128;
  unsigned short* wt_g2w1 = wt_g1w2 + 128*128;
  unsigned short* wt_g2w2 = wt_g2w1 + 256*128;
  unsigned short* wt_g3w1 = wt_g2w2 + 256*256;
  unsigned short* wt_g3w2 = wt_g3w1 + 512*256;
  unsigned short* wt_g4w1 = wt_g3w2 + 512*512;
  unsigned short* wt_g4w2 = wt_g4w1 + 256*512;
  unsigned short* wt_gat2 = wt_g4w2 + 256*256;   // [128][2048]

  double* st1 = statsA + 0;
  double* st2 = statsA + 256;
  double* st3 = statsA + 768;
  double* st4 = statsA + 1792;
  double* st5 = statsA + 2304;

  hipMemsetAsync(deg, 0, (size_t)((char*)(Bt_sc + 128*256) - (char*)deg), stream);

  k_hist3<<<(NE + NN + 1 + 255)/256, 256, 0, stream>>>(dst, batch, deg, gptr);
  k_scan1<<<1, 1024, 0, stream>>>(deg, rowptr);
  k_fill<<<(NE + 255)/256, 256, 0, stream>>>(src, dst, rowptr, cnt, csrc);

  {
    WPrep P;
    const float* Ws[9] = {gw1[0], gw2[0], gw1[1], gw2[1], gw1[2], gw2[2], gw1[3], gw2[3], gat_w};
    unsigned short* Wts[9] = {wt_g1w1, wt_g1w2, wt_g2w1, wt_g2w2, wt_g3w1, wt_g3w2, wt_g4w1, wt_g4w2, wt_gat2};
    int Ks[9]  = {128, 128, 128, 256, 256, 512, 512, 256, 256};
    int Nns[9] = {128, 128, 256, 256, 512, 512, 256, 256, 1024};
    int cum = 0;
    for (int i = 0; i < 9; i++){
      P.W[i] = Ws[i]; P.Wt[i] = Wts[i]; P.K[i] = Ks[i]; P.Nn[i] = Nns[i];
      P.tileStart[i] = cum;
      cum += (Ks[i] >> 6)*(Nns[i] >> 6);
    }
    P.tileStart[9] = cum;
    P.x = x; P.xb = (unsigned int*)xb;
    int xblocks = (NN*64 + 255)/256;
    P.xEnd = cum + xblocks;
    P.asrc = gat_asrc; P.adst = gat_adst; P.Bt_sc = Bt_sc;
    k_prep3<<<cum + xblocks + 16, 256, 0, stream>>>(P);
  }

  const int GM = (NN + 127) / 128;
  #define NB4 nullptr, nullptr, nullptr, nullptr

  // ---- GIN1 ----
  k_agg<0,64><<<NN/4, 256, 0, stream>>>((const unsigned int*)xb, rowptr, csrc, (unsigned int*)z16, nullptr, nullptr, nullptr, nullptr);
  k_gin1_mlp<<<GM, 256, 0, stream>>>(z16, wt_g1w1, gb1[0], wt_g1w2, gb2[0], hpre, st1, NN);

  // ---- GIN2 ----
  k_agg<1,64><<<NN/4, 256, 0, stream>>>((const unsigned int*)hpre, rowptr, csrc, (unsigned int*)z16, st1, bng[0], bnb[0], nullptr);
  k_gemm_mfma<1,1,0,0,0,0><<<dim3(2, GM), 256, 0, stream>>>(z16, wt_g2w1, gb1[1], nullptr, hid16, nullptr, NB4, NN, 256, 128);
  k_gemm_mfma<0,1,1,0,0,0><<<dim3(2, GM), 256, 0, stream>>>(hid16, wt_g2w2, gb2[1], nullptr, hpre, st2, NB4, NN, 256, 256);

  // ---- GIN3 ----
  k_agg<1,128><<<NN/2, 256, 0, stream>>>((const unsigned int*)hpre, rowptr, csrc, (unsigned int*)z16, st2, bng[1], bnb[1], nullptr);
  k_gemm_mfma<1,1,0,0,0,0><<<dim3(4, GM), 256, 0, stream>>>(z16, wt_g3w1, gb1[2], nullptr, hid16, nullptr, NB4, NN, 512, 256);
  k_gemm_mfma<0,1,1,0,0,0><<<dim3(4, GM), 256, 0, stream>>>(hid16, wt_g3w2, gb2[2], nullptr, hpre, st3, NB4, NN, 512, 512);

  // ---- GIN4 ----
  k_gemm_mfma<0,1,0,0,1,0><<<dim3(2, GM), 256, 0, stream>>>(hpre, wt_g4w1, nullptr, nullptr, hid16, nullptr, st3, bng[2], bnb[2], nullptr, NN, 256, 512);
  k_agg<2,128><<<NN/2, 256, 0, stream>>>((const unsigned int*)hid16, rowptr, csrc, (unsigned int*)z16, nullptr, nullptr, nullptr, gb1[3]);
  k_gemm_mfma<0,1,1,0,0,0><<<dim3(2, GM), 256, 0, stream>>>(z16, wt_g4w2, gb2[3], nullptr, hpre, st4, NB4, NN, 256, 256);

  // ---- GAT ----
  k_gemm_mfma<0,0,0,1,1,1><<<dim3(1, GM), 256, 0, stream>>>(hpre, Bt_sc, nullptr, a_sd, nullptr, nullptr, st4, bng[3], bnb[3], hb4, NN, 128, 256);
  k_gat_agg_w5<<<NN/4, 256, 0, stream>>>((const unsigned int*)hb4, a_sd, rowptr, csrc, (unsigned int*)agg16);
  k_gemm_mfma<0,1,1,0,0,0><<<dim3(1, GM), 256, 0, stream>>>(agg16, wt_gat2, gat_bias, nullptr, hpre, st5, NB4, NN, 128, 2048);

  k_bn_relu_gate<<<(NN*128/8 + 255)/256, 256, 0, stream>>>(hpre, hb, NN*128/8, st5, bng[4], bnb[4], gate_w, gate_b, logit);
  k_poolhead<<<NG, 128, 0, stream>>>(hb, logit, gptr, fc1_w, fc1_b, fc2_w, fc2_b, (float*)d_out);
}

// Round 14
// 512.009 us; speedup vs baseline: 1.0272x; 1.0272x over previous
//
#include <hip/hip_runtime.h>
#include <hip/hip_bf16.h>
#include <math.h>

#define NN 20000
#define NE 320000
#define NG 128

using bf16x8 = __attribute__((ext_vector_type(8))) short;
using f32x4  = __attribute__((ext_vector_type(4))) float;

static __device__ __forceinline__ float lrelu(float v){ return v > 0.f ? v : 0.2f*v; }
static __device__ __forceinline__ float b2f(unsigned short u){ unsigned int v = ((unsigned int)u) << 16; return __uint_as_float(v); }
static __device__ __forceinline__ unsigned short f2b(float f){
  unsigned int x = __float_as_uint(f);
  unsigned int r = x + 0x7fffu + ((x >> 16) & 1u);
  return (unsigned short)(r >> 16);
}
static __device__ __forceinline__ void gl16(const unsigned short* g, unsigned short* l){
  __builtin_amdgcn_global_load_lds((const __attribute__((address_space(1))) void*)g,
                                   (__attribute__((address_space(3))) void*)l, 16, 0, 0);
}
static __device__ __forceinline__ uint4 bn8(uint4 u, const float* scs, const float* shs, int f0){
  float v[8] = { b2f(u.x & 0xffff), b2f(u.x >> 16), b2f(u.y & 0xffff), b2f(u.y >> 16),
                 b2f(u.z & 0xffff), b2f(u.z >> 16), b2f(u.w & 0xffff), b2f(u.w >> 16) };
  #pragma unroll
  for (int j = 0; j < 8; j++) v[j] = fmaxf(v[j]*scs[f0 + j] + shs[f0 + j], 0.f);
  uint4 p;
  p.x = (unsigned int)f2b(v[0]) | ((unsigned int)f2b(v[1]) << 16);
  p.y = (unsigned int)f2b(v[2]) | ((unsigned int)f2b(v[3]) << 16);
  p.z = (unsigned int)f2b(v[4]) | ((unsigned int)f2b(v[5]) << 16);
  p.w = (unsigned int)f2b(v[6]) | ((unsigned int)f2b(v[7]) << 16);
  return p;
}

// ---------------- CSR build ----------------
__global__ void k_hist3(const int* __restrict__ dst, const int* __restrict__ batch,
                        int* __restrict__ deg, int* __restrict__ gptr){
  int i = blockIdx.x*blockDim.x + threadIdx.x;
  if (i < NE){
    atomicAdd(&deg[dst[i]], 1);
  } else if (i <= NE + NN){
    int j = i - NE;
    if (j == 0){
      int b0 = batch[0];
      for (int g = 0; g <= b0; g++) gptr[g] = 0;
    } else if (j < NN){
      int b0 = batch[j-1], b1 = batch[j];
      for (int g = b0 + 1; g <= b1; g++) gptr[g] = j;
    } else {
      int b0 = batch[NN-1];
      for (int g = b0 + 1; g <= NG; g++) gptr[g] = NN;
    }
  }
}

__global__ void k_scan1(const int* __restrict__ deg, int* __restrict__ rowptr){
  __shared__ int tmp[1024];
  int t = threadIdx.x;
  const int CH = 20;
  int lo = t*CH, hi = min(lo + CH, NN);
  int loc[CH];
  int s = 0;
  for (int i = lo; i < hi; i++){ loc[i - lo] = deg[i]; s += loc[i - lo]; }
  tmp[t] = s; __syncthreads();
  for (int off = 1; off < 1024; off <<= 1){
    int u = (t >= off) ? tmp[t - off] : 0;
    __syncthreads();
    tmp[t] += u;
    __syncthreads();
  }
  int r = tmp[t] - s;
  if (t == 0) rowptr[0] = 0;
  for (int i = lo; i < hi; i++){ r += loc[i - lo]; rowptr[i + 1] = r; }
}

__global__ void k_fill(const int* __restrict__ src, const int* __restrict__ dst,
                       const int* __restrict__ ptr, int* __restrict__ cnt,
                       int* __restrict__ csrc){
  int e = blockIdx.x*blockDim.x + threadIdx.x;
  if (e < NE){
    int d = dst[e];
    int p = atomicAdd(&cnt[d], 1);
    csrc[ptr[d] + p] = src[e];
  }
}

// ---------------- weight prep (+x cast +wasd, one kernel) ----------------
struct WPrep {
  const float* W[9];
  unsigned short* Wt[9];
  int K[9];
  int Nn[9];
  int tileStart[10];
  const float* x;
  unsigned int* xb;
  int xEnd;
  const float* asrc;
  const float* adst;
  unsigned short* Bt_sc;
};

__global__ __launch_bounds__(256)
void k_prep3(WPrep P){
  __shared__ float tile[64][65];
  __shared__ float av[128];
  int b = blockIdx.x;
  if (b < P.tileStart[9]){
    int i = 0;
    while (i < 8 && b >= P.tileStart[i+1]) i++;
    int ti = b - P.tileStart[i];
    int K = P.K[i], Nn = P.Nn[i];
    int ntc = Nn >> 6;
    int k0 = (ti / ntc) << 6, n0 = (ti % ntc) << 6;
    int c = threadIdx.x & 63, ro = threadIdx.x >> 6;
    const float* W = P.W[i];
    #pragma unroll
    for (int rr = 0; rr < 16; rr++){
      int r = rr*4 + ro;
      tile[c][r] = W[(size_t)(k0 + r)*Nn + n0 + c];
    }
    __syncthreads();
    unsigned short* Wt = P.Wt[i];
    if (i == 8){
      int hh = n0 >> 7, cl0 = n0 & 127;
      #pragma unroll
      for (int cc = 0; cc < 16; cc++){
        int cidx = cc*4 + ro;
        Wt[(size_t)(cl0 + cidx)*2048 + hh*256 + k0 + c] = f2b(tile[cidx][c]*0.125f);
      }
    } else {
      #pragma unroll
      for (int cc = 0; cc < 16; cc++){
        int cidx = cc*4 + ro;
        Wt[(size_t)(n0 + cidx)*K + k0 + c] = f2b(tile[cidx][c]);
      }
    }
  } else if (b < P.xEnd){
    int idx = (b - P.tileStart[9])*256 + threadIdx.x;
    if (idx < NN*64){
      unsigned int lo = f2b(P.x[2*idx]);
      unsigned int hi = f2b(P.x[2*idx + 1]);
      P.xb[idx] = lo | (hi << 16);
    }
  } else {
    int bb = b - P.xEnd;              // 0..15
    int h = bb & 7, isd = bb >> 3;
    int k = threadIdx.x;              // 0..255
    if (k < 128) av[k] = (isd ? P.adst : P.asrc)[h*128 + k];
    __syncthreads();
    const float* Wr = P.W[8] + (size_t)k*1024 + h*128;
    float s = 0.f;
    #pragma unroll 8
    for (int c = 0; c < 128; c++) s += Wr[c]*av[c];
    P.Bt_sc[bb*256 + k] = f2b(s);
  }
}

// ---------------- unified GIN aggregation (unroll-8) ----------------
template<int MODE, int DU>
__global__ __launch_bounds__(256)
void k_agg(const unsigned int* __restrict__ hU, const int* __restrict__ ptr,
           const int* __restrict__ csrc, unsigned int* __restrict__ z,
           const double* __restrict__ stats, const float* __restrict__ g,
           const float* __restrict__ bb, const float* __restrict__ bias){
  const int d = DU*2;
  __shared__ float scs[MODE == 1 ? 512 : 1];
  __shared__ float shs[MODE == 1 ? 512 : 1];
  int t = threadIdx.x;
  if (MODE == 1){
    for (int f = t; f < d; f += 256){
      double inv = 1.0 / (double)NN;
      double mu  = stats[f]*inv;
      double var = stats[d + f]*inv - mu*mu;
      if (var < 0.0) var = 0.0;
      float sc = g[f] * rsqrtf((float)var + 1e-5f);
      scs[f] = sc;
      shs[f] = bb[f] - (float)mu*sc;
    }
    __syncthreads();
  }
  const int npb = 256/DU;
  int n  = blockIdx.x*npb + t/DU;
  int tl = t & (DU - 1);
  int f0 = 2*tl, f1 = f0 + 1;
  float sc0 = 0.f, sh0 = 0.f, sc1 = 0.f, sh1 = 0.f;
  if (MODE == 1){ sc0 = scs[f0]; sh0 = shs[f0]; sc1 = scs[f1]; sh1 = shs[f1]; }
  int beg = ptr[n], deg = ptr[n+1] - beg;
  unsigned int self = hU[(size_t)n*DU + tl];
  float a0, a1;
  if (MODE == 1){
    a0 = fmaxf(b2f(self & 0xffff)*sc0 + sh0, 0.f);
    a1 = fmaxf(b2f(self >> 16)   *sc1 + sh1, 0.f);
  } else {
    a0 = b2f(self & 0xffff);
    a1 = b2f(self >> 16);
  }
  int i = 0;
  for (; i + 8 <= deg; i += 8){
    unsigned int v[8];
    #pragma unroll
    for (int u = 0; u < 8; u++) v[u] = hU[(size_t)csrc[beg + i + u]*DU + tl];
    #pragma unroll
    for (int u = 0; u < 8; u++){
      if (MODE == 1){
        a0 += fmaxf(b2f(v[u] & 0xffff)*sc0 + sh0, 0.f);
        a1 += fmaxf(b2f(v[u] >> 16)   *sc1 + sh1, 0.f);
      } else {
        a0 += b2f(v[u] & 0xffff);
        a1 += b2f(v[u] >> 16);
      }
    }
  }
  for (; i < deg; i++){
    unsigned int v = hU[(size_t)csrc[beg + i]*DU + tl];
    if (MODE == 1){
      a0 += fmaxf(b2f(v & 0xffff)*sc0 + sh0, 0.f);
      a1 += fmaxf(b2f(v >> 16)   *sc1 + sh1, 0.f);
    } else {
      a0 += b2f(v & 0xffff);
      a1 += b2f(v >> 16);
    }
  }
  if (MODE == 2){
    a0 = fmaxf(a0 + bias[f0], 0.f);
    a1 = fmaxf(a1 + bias[f1], 0.f);
  }
  z[(size_t)n*DU + tl] = (unsigned int)f2b(a0) | ((unsigned int)f2b(a1) << 16);
}

// ---------------- bf16 MFMA GEMM ----------------
template<int ACT, int OBF, int STATS, int PK, int BNA, int WBA>
__global__ __launch_bounds__(256)
void k_gemm_mfma(const unsigned short* __restrict__ A, const unsigned short* __restrict__ Bt,
                 const float* __restrict__ bias, float* __restrict__ C,
                 unsigned short* __restrict__ Cb, double* __restrict__ stats,
                 const double* __restrict__ bnst, const float* __restrict__ bng,
                 const float* __restrict__ bnb, unsigned short* __restrict__ Awb,
                 int M, int Nn, int K){
  const int LDA = BNA ? 40 : 32;
  __shared__ unsigned short As[2][128*(BNA ? 40 : 32)];
  __shared__ unsigned short Bs[2][128*32];
  __shared__ float scs[BNA ? 512 : 1];
  __shared__ float shs[BNA ? 512 : 1];
  const int bm = blockIdx.y*128, bn = blockIdx.x*128;
  const int tid = threadIdx.x;
  const int lane = tid & 63;
  const int wave = tid >> 6;
  const int wm = (wave >> 1)*64, wn = (wave & 1)*64;
  const int lr = lane & 15, lq = lane >> 4;

  f32x4 acc[4][4];
  #pragma unroll
  for (int i = 0; i < 4; i++)
    #pragma unroll
    for (int j = 0; j < 4; j++) acc[i][j] = (f32x4){0.f,0.f,0.f,0.f};

  const int rowA = tid >> 2, q = tid & 3;
  const int ldsOff = wave*16*32;
  const int gmA0 = min(bm + rowA,      M-1);
  const int gmA1 = min(bm + rowA + 64, M-1);
  const unsigned short* pA0 = &A[(size_t)gmA0*K + q*8];
  const unsigned short* pA1 = &A[(size_t)gmA1*K + q*8];
  const unsigned short* pB0 = &Bt[(size_t)(bn + rowA)*K + q*8];
  const unsigned short* pB1 = &Bt[(size_t)(bn + rowA + 64)*K + q*8];

  if (BNA){
    for (int f = tid; f < K; f += 256){
      double inv = 1.0 / (double)NN;
      double mu  = bnst[f]*inv;
      double var = bnst[K + f]*inv - mu*mu;
      if (var < 0.0) var = 0.0;
      float sc = bng[f] * rsqrtf((float)var + 1e-5f);
      scs[f] = sc;
      shs[f] = bnb[f] - (float)mu*sc;
    }
    __syncthreads();
  }

  if (BNA){
    uint4 u0 = *(const uint4*)pA0;
    uint4 u1 = *(const uint4*)pA1;
    int f0 = q*8;
    uint4 w0 = bn8(u0, scs, shs, f0);
    uint4 w1 = bn8(u1, scs, shs, f0);
    *(uint4*)&As[0][ rowA      *LDA + q*8] = w0;
    *(uint4*)&As[0][(rowA + 64)*LDA + q*8] = w1;
    if (WBA){
      *(uint4*)&Awb[(size_t)gmA0*K + q*8] = w0;
      *(uint4*)&Awb[(size_t)gmA1*K + q*8] = w1;
    }
  } else {
    gl16(pA0, &As[0][ldsOff]);
    gl16(pA1, &As[0][ldsOff] + 64*32);
  }
  gl16(pB0, &Bs[0][ldsOff]);
  gl16(pB1, &Bs[0][ldsOff] + 64*32);
  __syncthreads();

  int cur = 0;
  for (int k0 = 0; k0 < K; k0 += 32){
    const int kn = k0 + 32;
    uint4 nu0, nu1;
    if (kn < K){
      if (BNA){
        nu0 = *(const uint4*)(pA0 + kn);
        nu1 = *(const uint4*)(pA1 + kn);
      } else {
        gl16(pA0 + kn, &As[cur^1][ldsOff]);
        gl16(pA1 + kn, &As[cur^1][ldsOff] + 64*32);
      }
      gl16(pB0 + kn, &Bs[cur^1][ldsOff]);
      gl16(pB1 + kn, &Bs[cur^1][ldsOff] + 64*32);
    }
    bf16x8 af[4], bf[4];
    #pragma unroll
    for (int mi = 0; mi < 4; mi++)
      af[mi] = *(const bf16x8*)&As[cur][(wm + mi*16 + lr)*LDA + lq*8];
    #pragma unroll
    for (int ni = 0; ni < 4; ni++)
      bf[ni] = *(const bf16x8*)&Bs[cur][(wn + ni*16 + lr)*32 + lq*8];
    #pragma unroll
    for (int mi = 0; mi < 4; mi++)
      #pragma unroll
      for (int ni = 0; ni < 4; ni++)
        acc[mi][ni] = __builtin_amdgcn_mfma_f32_16x16x32_bf16(af[mi], bf[ni], acc[mi][ni], 0, 0, 0);
    if (BNA && kn < K){
      int f0 = kn + q*8;
      uint4 w0 = bn8(nu0, scs, shs, f0);
      uint4 w1 = bn8(nu1, scs, shs, f0);
      *(uint4*)&As[cur^1][ rowA      *LDA + q*8] = w0;
      *(uint4*)&As[cur^1][(rowA + 64)*LDA + q*8] = w1;
      if (WBA){
        *(uint4*)&Awb[(size_t)gmA0*K + kn + q*8] = w0;
        *(uint4*)&Awb[(size_t)gmA1*K + kn + q*8] = w1;
      }
    }
    __syncthreads();
    cur ^= 1;
  }

  float cs[4] = {0.f,0.f,0.f,0.f}, cq[4] = {0.f,0.f,0.f,0.f};
  #pragma unroll
  for (int mi = 0; mi < 4; mi++){
    #pragma unroll
    for (int j = 0; j < 4; j++){
      int gm = bm + wm + mi*16 + lq*4 + j;
      if (gm < M){
        #pragma unroll
        for (int ni = 0; ni < 4; ni++){
          int gn = bn + wn + ni*16 + lr;
          float v = acc[mi][ni][j] + (bias ? bias[gn] : 0.f);
          if (ACT) v = fmaxf(v, 0.f);
          if (PK){ if (gn < 16) C[(size_t)gm*16 + gn] = v; }
          else if (OBF) Cb[(size_t)gm*Nn + gn] = f2b(v);
          else     C [(size_t)gm*Nn + gn] = v;
          if (STATS){ cs[ni] += v; cq[ni] += v*v; }
        }
      }
    }
  }
  if (STATS){
    #pragma unroll
    for (int ni = 0; ni < 4; ni++){
      float s = cs[ni], qq = cq[ni];
      s += __shfl_xor(s, 16); s += __shfl_xor(s, 32);
      qq += __shfl_xor(qq, 16); qq += __shfl_xor(qq, 32);
      if (lane < 16){
        int gn = bn + wn + ni*16 + lr;
        atomicAdd(&stats[gn],      (double)s);
        atomicAdd(&stats[Nn + gn], (double)qq);
      }
    }
  }
}

// ---------------- fused GIN1 MLP ----------------
__global__ __launch_bounds__(256)
void k_gin1_mlp(const unsigned short* __restrict__ Z, const unsigned short* __restrict__ W1t,
                const float* __restrict__ b1, const unsigned short* __restrict__ W2t,
                const float* __restrict__ b2, unsigned short* __restrict__ Out,
                double* __restrict__ stats, int M){
  __shared__ unsigned short As[2][128*32];
  __shared__ unsigned short Bs[2][128*32];
  __shared__ unsigned short hid[128*136];
  const int bm = blockIdx.x*128;
  const int tid = threadIdx.x;
  const int lane = tid & 63;
  const int wave = tid >> 6;
  const int wm = (wave >> 1)*64, wn = (wave & 1)*64;
  const int lr = lane & 15, lq = lane >> 4;
  const int rowA = tid >> 2, q = tid & 3;
  const int ldsOff = wave*16*32;
  const int gm0 = min(bm + rowA,      M-1);
  const int gm1 = min(bm + rowA + 64, M-1);
  const unsigned short* pA0 = &Z[(size_t)gm0*128 + q*8];
  const unsigned short* pA1 = &Z[(size_t)gm1*128 + q*8];
  const unsigned short* pB0 = &W1t[(size_t)rowA*128 + q*8];
  const unsigned short* pB1 = &W1t[(size_t)(rowA + 64)*128 + q*8];

  f32x4 acc[4][4];
  #pragma unroll
  for (int i = 0; i < 4; i++)
    #pragma unroll
    for (int j = 0; j < 4; j++) acc[i][j] = (f32x4){0.f,0.f,0.f,0.f};

  gl16(pA0, &As[0][ldsOff]);
  gl16(pA1, &As[0][ldsOff] + 64*32);
  gl16(pB0, &Bs[0][ldsOff]);
  gl16(pB1, &Bs[0][ldsOff] + 64*32);
  __syncthreads();
  int cur = 0;
  for (int k0 = 0; k0 < 128; k0 += 32){
    int kn = k0 + 32;
    if (kn < 128){
      gl16(pA0 + kn, &As[cur^1][ldsOff]);
      gl16(pA1 + kn, &As[cur^1][ldsOff] + 64*32);
      gl16(pB0 + kn, &Bs[cur^1][ldsOff]);
      gl16(pB1 + kn, &Bs[cur^1][ldsOff] + 64*32);
    }
    bf16x8 af[4], bf[4];
    #pragma unroll
    for (int mi = 0; mi < 4; mi++)
      af[mi] = *(const bf16x8*)&As[cur][(wm + mi*16 + lr)*32 + lq*8];
    #pragma unroll
    for (int ni = 0; ni < 4; ni++)
      bf[ni] = *(const bf16x8*)&Bs[cur][(wn + ni*16 + lr)*32 + lq*8];
    #pragma unroll
    for (int mi = 0; mi < 4; mi++)
      #pragma unroll
      for (int ni = 0; ni < 4; ni++)
        acc[mi][ni] = __builtin_amdgcn_mfma_f32_16x16x32_bf16(af[mi], bf[ni], acc[mi][ni], 0, 0, 0);
    __syncthreads();
    cur ^= 1;
  }
  {
    float bv[4];
    #pragma unroll
    for (int ni = 0; ni < 4; ni++) bv[ni] = b1[wn + ni*16 + lr];
    #pragma unroll
    for (int mi = 0; mi < 4; mi++)
      #pragma unroll
      for (int j = 0; j < 4; j++){
        int row = wm + mi*16 + lq*4 + j;
        #pragma unroll
        for (int ni = 0; ni < 4; ni++){
          int col = wn + ni*16 + lr;
          hid[row*136 + col] = f2b(fmaxf(acc[mi][ni][j] + bv[ni], 0.f));
        }
      }
  }
  __syncthreads();

  f32x4 acc2[4][4];
  #pragma unroll
  for (int i = 0; i < 4; i++)
    #pragma unroll
    for (int j = 0; j < 4; j++) acc2[i][j] = (f32x4){0.f,0.f,0.f,0.f};
  const unsigned short* pC0 = &W2t[(size_t)rowA*128 + q*8];
  const unsigned short* pC1 = &W2t[(size_t)(rowA + 64)*128 + q*8];
  gl16(pC0, &Bs[0][ldsOff]);
  gl16(pC1, &Bs[0][ldsOff] + 64*32);
  __syncthreads();
  cur = 0;
  for (int k0 = 0; k0 < 128; k0 += 32){
    int kn = k0 + 32;
    if (kn < 128){
      gl16(pC0 + kn, &Bs[cur^1][ldsOff]);
      gl16(pC1 + kn, &Bs[cur^1][ldsOff] + 64*32);
    }
    bf16x8 af[4], bf[4];
    #pragma unroll
    for (int mi = 0; mi < 4; mi++)
      af[mi] = *(const bf16x8*)&hid[(wm + mi*16 + lr)*136 + k0 + lq*8];
    #pragma unroll
    for (int ni = 0; ni < 4; ni++)
      bf[ni] = *(const bf16x8*)&Bs[cur][(wn + ni*16 + lr)*32 + lq*8];
    #pragma unroll
    for (int mi = 0; mi < 4; mi++)
      #pragma unroll
      for (int ni = 0; ni < 4; ni++)
        acc2[mi][ni] = __builtin_amdgcn_mfma_f32_16x16x32_bf16(af[mi], bf[ni], acc2[mi][ni], 0, 0, 0);
    __syncthreads();
    cur ^= 1;
  }
  float cs[4] = {0.f,0.f,0.f,0.f}, cq[4] = {0.f,0.f,0.f,0.f};
  #pragma unroll
  for (int mi = 0; mi < 4; mi++){
    #pragma unroll
    for (int j = 0; j < 4; j++){
      int gm = bm + wm + mi*16 + lq*4 + j;
      if (gm < M){
        #pragma unroll
        for (int ni = 0; ni < 4; ni++){
          int gn = wn + ni*16 + lr;
          float v = acc2[mi][ni][j] + b2[gn];
          Out[(size_t)gm*128 + gn] = f2b(v);
          cs[ni] += v; cq[ni] += v*v;
        }
      }
    }
  }
  #pragma unroll
  for (int ni = 0; ni < 4; ni++){
    float s = cs[ni], qq = cq[ni];
    s += __shfl_xor(s, 16); s += __shfl_xor(s, 32);
    qq += __shfl_xor(qq, 16); qq += __shfl_xor(qq, 32);
    if (lane < 16){
      int gn = wn + ni*16 + lr;
      atomicAdd(&stats[gn],       (double)s);
      atomicAdd(&stats[128 + gn], (double)qq);
    }
  }
}

// ---------------- GAT: wave-per-node (round-12 best structure), pre-BN'd values ----------------
__global__ __launch_bounds__(256)
void k_gat_agg_w4(const unsigned int* __restrict__ hU4, const float* __restrict__ a_sd,
                  const int* __restrict__ ptr, const int* __restrict__ csrc,
                  unsigned int* __restrict__ agg){
  int wv = threadIdx.x >> 6, lane = threadIdx.x & 63;
  int n = blockIdx.x*4 + wv;
  int eslot = lane >> 3, hh = lane & 7;
  float adn = a_sd[n*16 + 8 + hh];
  int beg = ptr[n], deg = ptr[n+1] - beg, tot = deg + 1;

  float scb[8];
  int   sb[8];
  float m = -1e30f;
  #pragma unroll
  for (int c = 0; c < 8; c++){
    int e = c*8 + eslot;
    int s_ = (e < deg) ? csrc[beg + e] : n;
    sb[c] = s_;
    float v = (e < tot) ? lrelu(a_sd[s_*16 + hh] + adn) : -1e30f;
    scb[c] = v;
    m = fmaxf(m, v);
  }
  for (int e = 64 + eslot; e < tot; e += 8){
    int s_ = (e < deg) ? csrc[beg + e] : n;
    m = fmaxf(m, lrelu(a_sd[s_*16 + hh] + adn));
  }
  m = fmaxf(m, __shfl_xor(m, 8));
  m = fmaxf(m, __shfl_xor(m, 16));
  m = fmaxf(m, __shfl_xor(m, 32));
  float S = 0.f;
  #pragma unroll
  for (int c = 0; c < 8; c++){
    float e_ = __expf(scb[c] - m);
    scb[c] = e_;
    S += e_;
  }
  for (int e = 64 + eslot; e < tot; e += 8){
    int s_ = (e < deg) ? csrc[beg + e] : n;
    S += __expf(lrelu(a_sd[s_*16 + hh] + adn) - m);
  }
  S += __shfl_xor(S, 8); S += __shfl_xor(S, 16); S += __shfl_xor(S, 32);
  float rinv = 1.f / (S + 1e-16f);
  #pragma unroll
  for (int c = 0; c < 8; c++) scb[c] *= rinv;

  float acc[8][4];
  #pragma unroll
  for (int h = 0; h < 8; h++)
    #pragma unroll
    for (int j = 0; j < 4; j++) acc[h][j] = 0.f;

  #pragma unroll
  for (int c = 0; c < 8; c++){
    int ebase = c*8;
    if (ebase >= tot) break;
    int   sbc  = sb[c];
    float scbc = scb[c];
    #pragma unroll
    for (int ee = 0; ee < 8; ee++){
      int e = ebase + ee;
      if (e >= tot) break;
      int sl = ee*8;
      int srcN = __shfl(sbc, sl);
      float al[8];
      #pragma unroll
      for (int h = 0; h < 8; h++) al[h] = __shfl(scbc, sl + h);
      uint2 u = *(const uint2*)&hU4[(size_t)srcN*128 + lane*2];
      float v0 = b2f(u.x & 0xffff);
      float v1 = b2f(u.x >> 16);
      float v2 = b2f(u.y & 0xffff);
      float v3 = b2f(u.y >> 16);
      #pragma unroll
      for (int h = 0; h < 8; h++){
        acc[h][0] += al[h]*v0; acc[h][1] += al[h]*v1;
        acc[h][2] += al[h]*v2; acc[h][3] += al[h]*v3;
      }
    }
  }
  for (int e = 64; e < tot; e++){
    int s_ = (e < deg) ? csrc[beg + e] : n;
    float a = __expf(lrelu(a_sd[s_*16 + hh] + adn) - m)*rinv;
    float al[8];
    #pragma unroll
    for (int h = 0; h < 8; h++) al[h] = __shfl(a, h);
    uint2 u = *(const uint2*)&hU4[(size_t)s_*128 + lane*2];
    float v0 = b2f(u.x & 0xffff), v1 = b2f(u.x >> 16);
    float v2 = b2f(u.y & 0xffff), v3 = b2f(u.y >> 16);
    #pragma unroll
    for (int h = 0; h < 8; h++){
      acc[h][0] += al[h]*v0; acc[h][1] += al[h]*v1;
      acc[h][2] += al[h]*v2; acc[h][3] += al[h]*v3;
    }
  }

  #pragma unroll
  for (int h = 0; h < 8; h++){
    uint2 o;
    o.x = (unsigned int)f2b(acc[h][0]) | ((unsigned int)f2b(acc[h][1]) << 16);
    o.y = (unsigned int)f2b(acc[h][2]) | ((unsigned int)f2b(acc[h][3]) << 16);
    *(uint2*)&agg[(size_t)n*1024 + h*128 + lane*2] = o;
  }
}

// ---------------- BN5 + gate ----------------
__global__ __launch_bounds__(256)
void k_bn_relu_gate(const unsigned short* __restrict__ hpre, unsigned short* __restrict__ hb,
                    int total8, const double* __restrict__ stats,
                    const float* __restrict__ g, const float* __restrict__ b,
                    const float* __restrict__ gatew, const float* __restrict__ gateb,
                    float* __restrict__ logit){
  const int d = 128;
  __shared__ float scs[128], shs[128];
  for (int f = threadIdx.x; f < d; f += blockDim.x){
    double inv = 1.0 / (double)NN;
    double mu  = stats[f]*inv;
    double var = stats[d + f]*inv - mu*mu;
    if (var < 0.0) var = 0.0;
    float sc = g[f] * rsqrtf((float)var + 1e-5f);
    scs[f] = sc;
    shs[f] = b[f] - (float)mu*sc;
  }
  __syncthreads();
  int i = blockIdx.x*blockDim.x + threadIdx.x;
  if (i >= total8) return;
  int i8 = i*8;
  uint4 u = *(const uint4*)&hpre[i8];
  float v[8] = { b2f(u.x & 0xffff), b2f(u.x >> 16), b2f(u.y & 0xffff), b2f(u.y >> 16),
                 b2f(u.z & 0xffff), b2f(u.z >> 16), b2f(u.w & 0xffff), b2f(u.w >> 16) };
  int f0 = i8 & 127;
  float gp = 0.f;
  #pragma unroll
  for (int j = 0; j < 8; j++){
    float y = fmaxf(v[j]*scs[f0 + j] + shs[f0 + j], 0.f);
    v[j] = y;
    gp += y*gatew[f0 + j];
  }
  uint4 p;
  p.x = (unsigned int)f2b(v[0]) | ((unsigned int)f2b(v[1]) << 16);
  p.y = (unsigned int)f2b(v[2]) | ((unsigned int)f2b(v[3]) << 16);
  p.z = (unsigned int)f2b(v[4]) | ((unsigned int)f2b(v[5]) << 16);
  p.w = (unsigned int)f2b(v[6]) | ((unsigned int)f2b(v[7]) << 16);
  *(uint4*)&hb[i8] = p;
  #pragma unroll
  for (int o = 1; o < 16; o <<= 1) gp += __shfl_xor(gp, o);
  if ((threadIdx.x & 15) == 0) logit[i >> 4] = gp + gateb[0];
}

// ---------------- pooling + head fused ----------------
__global__ void k_poolhead(const unsigned short* __restrict__ h, const float* __restrict__ logit,
                           const int* __restrict__ gptr,
                           const float* __restrict__ w1, const float* __restrict__ b1,
                           const float* __restrict__ w2, const float* __restrict__ b2,
                           float* __restrict__ out){
  int g = blockIdx.x, t = threadIdx.x;   // 128
  int beg = gptr[g], end = gptr[g+1];
  __shared__ float red[128];
  __shared__ float prow[128];
  __shared__ float r1[128];
  __shared__ float m_sh, s_sh;
  float mx = -1e30f;
  for (int i = beg + t; i < end; i += 128) mx = fmaxf(mx, logit[i]);
  red[t] = mx; __syncthreads();
  for (int off = 64; off > 0; off >>= 1){ if (t < off) red[t] = fmaxf(red[t], red[t + off]); __syncthreads(); }
  if (t == 0) m_sh = red[0];
  __syncthreads();
  float sm = 0.f;
  for (int i = beg + t; i < end; i += 128) sm += __expf(logit[i] - m_sh);
  red[t] = sm; __syncthreads();
  for (int off = 64; off > 0; off >>= 1){ if (t < off) red[t] += red[t + off]; __syncthreads(); }
  if (t == 0) s_sh = red[0] + 1e-16f;
  __syncthreads();
  float acc = 0.f;
  for (int i = beg; i < end; i++){
    float w = __expf(logit[i] - m_sh) / s_sh;
    acc += w * b2f(h[(size_t)i*128 + t]);
  }
  prow[t] = acc;
  __syncthreads();
  float a = b1[t];
  for (int k = 0; k < 128; k++) a += prow[k]*w1[k*128 + t];
  a = fmaxf(a, 0.f);
  red[t] = a*w2[t*2 + 0]; r1[t] = a*w2[t*2 + 1];
  __syncthreads();
  for (int off = 64; off > 0; off >>= 1){
    if (t < off){ red[t] += red[t + off]; r1[t] += r1[t + off]; }
    __syncthreads();
  }
  if (t == 0){ out[g*2 + 0] = red[0] + b2[0]; out[g*2 + 1] = r1[0] + b2[1]; }
}

extern "C" void kernel_launch(void* const* d_in, const int* in_sizes, int n_in,
                              void* d_out, int out_size, void* d_ws, size_t ws_size,
                              hipStream_t stream) {
  const float* x        = (const float*)d_in[0];
  const int*   ei       = (const int*)  d_in[1];
  const int*   batch    = (const int*)  d_in[2];
  const float* gw1[4] = {(const float*)d_in[3],  (const float*)d_in[7],  (const float*)d_in[11], (const float*)d_in[15]};
  const float* gb1[4] = {(const float*)d_in[4],  (const float*)d_in[8],  (const float*)d_in[12], (const float*)d_in[16]};
  const float* gw2[4] = {(const float*)d_in[5],  (const float*)d_in[9],  (const float*)d_in[13], (const float*)d_in[17]};
  const float* gb2[4] = {(const float*)d_in[6],  (const float*)d_in[10], (const float*)d_in[14], (const float*)d_in[18]};
  const float* bng[5] = {(const float*)d_in[19], (const float*)d_in[21], (const float*)d_in[23], (const float*)d_in[25], (const float*)d_in[27]};
  const float* bnb[5] = {(const float*)d_in[20], (const float*)d_in[22], (const float*)d_in[24], (const float*)d_in[26], (const float*)d_in[28]};
  const float* gat_w    = (const float*)d_in[29];
  const float* gat_asrc = (const float*)d_in[30];
  const float* gat_adst = (const float*)d_in[31];
  const float* gat_bias = (const float*)d_in[32];
  const float* gate_w   = (const float*)d_in[33];
  const float* gate_b   = (const float*)d_in[34];
  const float* fc1_w    = (const float*)d_in[35];
  const float* fc1_b    = (const float*)d_in[36];
  const float* fc2_w    = (const float*)d_in[37];
  const float* fc2_b    = (const float*)d_in[38];
  const int* src = ei;
  const int* dst = ei + NE;

  char* wsb = (char*)d_ws;
  size_t off = 0;
  auto take = [&](size_t bytes) -> void* {
    void* p = wsb + off;
    off = (off + bytes + 255) & ~(size_t)255;
    return p;
  };
  unsigned short* hpre  = (unsigned short*)take((size_t)NN*512*2);
  unsigned short* hb    = (unsigned short*)take((size_t)NN*128*2);
  unsigned short* hb4   = (unsigned short*)take((size_t)NN*256*2);
  unsigned short* R     = (unsigned short*)take((size_t)NN*2048*2);
  unsigned short* z16   = R;
  unsigned short* hid16 = R + (size_t)NN*512;
  unsigned short* agg16 = R;
  unsigned short* xb    = (unsigned short*)take((size_t)NN*128*2);
  unsigned short* wt    = (unsigned short*)take((size_t)1000000*2);
  int*    deg    = (int*)   take((size_t)NN*4);
  int*    cnt    = (int*)   take((size_t)NN*4);
  double* statsA = (double*)take(2560*8);
  unsigned short* Bt_sc = (unsigned short*)take((size_t)128*256*2);
  float*  a_sd   = (float*) take((size_t)NN*16*4);
  float*  logit  = (float*) take((size_t)NN*4);
  int*    rowptr = (int*)   take((size_t)(NN+1)*4);
  int*    gptr   = (int*)   take((size_t)(NG+1)*4);
  int*    csrc   = (int*)   take((size_t)NE*4);
  (void)ws_size; (void)n_in; (void)in_sizes; (void)out_size;

  unsigned short* wt_g1w1 = wt;
  unsigned short* wt_g1w2 = wt_g1w1 + 128*128;
  unsigned short* wt_g2w1 = wt_g1w2 + 128*128;
  unsigned short* wt_g2w2 = wt_g2w1 + 256*128;
  unsigned short* wt_g3w1 = wt_g2w2 + 256*256;
  unsigned short* wt_g3w2 = wt_g3w1 + 512*256;
  unsigned short* wt_g4w1 = wt_g3w2 + 512*512;
  unsigned short* wt_g4w2 = wt_g4w1 + 256*512;
  unsigned short* wt_gat2 = wt_g4w2 + 256*256;   // [128][2048]

  double* st1 = statsA + 0;
  double* st2 = statsA + 256;
  double* st3 = statsA + 768;
  double* st4 = statsA + 1792;
  double* st5 = statsA + 2304;

  hipMemsetAsync(deg, 0, (size_t)((char*)(Bt_sc + 128*256) - (char*)deg), stream);

  k_hist3<<<(NE + NN + 1 + 255)/256, 256, 0, stream>>>(dst, batch, deg, gptr);
  k_scan1<<<1, 1024, 0, stream>>>(deg, rowptr);
  k_fill<<<(NE + 255)/256, 256, 0, stream>>>(src, dst, rowptr, cnt, csrc);

  {
    WPrep P;
    const float* Ws[9] = {gw1[0], gw2[0], gw1[1], gw2[1], gw1[2], gw2[2], gw1[3], gw2[3], gat_w};
    unsigned short* Wts[9] = {wt_g1w1, wt_g1w2, wt_g2w1, wt_g2w2, wt_g3w1, wt_g3w2, wt_g4w1, wt_g4w2, wt_gat2};
    int Ks[9]  = {128, 128, 128, 256, 256, 512, 512, 256, 256};
    int Nns[9] = {128, 128, 256, 256, 512, 512, 256, 256, 1024};
    int cum = 0;
    for (int i = 0; i < 9; i++){
      P.W[i] = Ws[i]; P.Wt[i] = Wts[i]; P.K[i] = Ks[i]; P.Nn[i] = Nns[i];
      P.tileStart[i] = cum;
      cum += (Ks[i] >> 6)*(Nns[i] >> 6);
    }
    P.tileStart[9] = cum;
    P.x = x; P.xb = (unsigned int*)xb;
    int xblocks = (NN*64 + 255)/256;
    P.xEnd = cum + xblocks;
    P.asrc = gat_asrc; P.adst = gat_adst; P.Bt_sc = Bt_sc;
    k_prep3<<<cum + xblocks + 16, 256, 0, stream>>>(P);
  }

  const int GM = (NN + 127) / 128;
  #define NB4 nullptr, nullptr, nullptr, nullptr

  // ---- GIN1 ----
  k_agg<0,64><<<NN/4, 256, 0, stream>>>((const unsigned int*)xb, rowptr, csrc, (unsigned int*)z16, nullptr, nullptr, nullptr, nullptr);
  k_gin1_mlp<<<GM, 256, 0, stream>>>(z16, wt_g1w1, gb1[0], wt_g1w2, gb2[0], hpre, st1, NN);

  // ---- GIN2 ----
  k_agg<1,64><<<NN/4, 256, 0, stream>>>((const unsigned int*)hpre, rowptr, csrc, (unsigned int*)z16, st1, bng[0], bnb[0], nullptr);
  k_gemm_mfma<1,1,0,0,0,0><<<dim3(2, GM), 256, 0, stream>>>(z16, wt_g2w1, gb1[1], nullptr, hid16, nullptr, NB4, NN, 256, 128);
  k_gemm_mfma<0,1,1,0,0,0><<<dim3(2, GM), 256, 0, stream>>>(hid16, wt_g2w2, gb2[1], nullptr, hpre, st2, NB4, NN, 256, 256);

  // ---- GIN3 ----
  k_agg<1,128><<<NN/2, 256, 0, stream>>>((const unsigned int*)hpre, rowptr, csrc, (unsigned int*)z16, st2, bng[1], bnb[1], nullptr);
  k_gemm_mfma<1,1,0,0,0,0><<<dim3(4, GM), 256, 0, stream>>>(z16, wt_g3w1, gb1[2], nullptr, hid16, nullptr, NB4, NN, 512, 256);
  k_gemm_mfma<0,1,1,0,0,0><<<dim3(4, GM), 256, 0, stream>>>(hid16, wt_g3w2, gb2[2], nullptr, hpre, st3, NB4, NN, 512, 512);

  // ---- GIN4 ----
  k_gemm_mfma<0,1,0,0,1,0><<<dim3(2, GM), 256, 0, stream>>>(hpre, wt_g4w1, nullptr, nullptr, hid16, nullptr, st3, bng[2], bnb[2], nullptr, NN, 256, 512);
  k_agg<2,128><<<NN/2, 256, 0, stream>>>((const unsigned int*)hid16, rowptr, csrc, (unsigned int*)z16, nullptr, nullptr, nullptr, gb1[3]);
  k_gemm_mfma<0,1,1,0,0,0><<<dim3(2, GM), 256, 0, stream>>>(z16, wt_g4w2, gb2[3], nullptr, hpre, st4, NB4, NN, 256, 256);

  // ---- GAT ----
  k_gemm_mfma<0,0,0,1,1,1><<<dim3(1, GM), 256, 0, stream>>>(hpre, Bt_sc, nullptr, a_sd, nullptr, nullptr, st4, bng[3], bnb[3], hb4, NN, 128, 256);
  k_gat_agg_w4<<<NN/4, 256, 0, stream>>>((const unsigned int*)hb4, a_sd, rowptr, csrc, (unsigned int*)agg16);
  k_gemm_mfma<0,1,1,0,0,0><<<dim3(1, GM), 256, 0, stream>>>(agg16, wt_gat2, gat_bias, nullptr, hpre, st5, NB4, NN, 128, 2048);

  k_bn_relu_gate<<<(NN*128/8 + 255)/256, 256, 0, stream>>>(hpre, hb, NN*128/8, st5, bng[4], bnb[4], gate_w, gate_b, logit);
  k_poolhead<<<NG, 128, 0, stream>>>(hb, logit, gptr, fc1_w, fc1_b, fc2_w, fc2_b, (float*)d_out);
}